// Round 17
// baseline (239.880 us; speedup 1.0000x reference)
//
#include <hip/hip_runtime.h>
#include <math.h>

// FourierConv2D: B=16,H=W=128,C=16,F=32. FFT 256x256, half-spectrum w in [0,129).
// v16: k3+k4 FUSED (k34): per (b-group-of-4, w) block, einsum all 256 h via MFMA into a
// 128KB LDS [h][4b*32f] buffer (packed bf16), then 128 in-place column iFFTs (in-column
// bf16 scratch, no extra LDS), crop y, coalesced T store. OF intermediate eliminated
// (-135MB HBM). k1/k2/k5 = v15.

constexpr int Bn = 16, Cc = 16, Ff = 32, Hh = 128, Ww = 128, Nn = 256, WH = 129;

#define DEVINL __device__ __forceinline__
DEVINL float2 f2(float a, float b) { return make_float2(a, b); }
DEVINL float2 cmul(float2 a, float2 b) { return f2(a.x * b.x - a.y * b.y, a.x * b.y + a.y * b.x); }

DEVINL unsigned short f2bf(float f) { unsigned u = __float_as_uint(f); return (unsigned short)((u + 0x8000u) >> 16); }
DEVINL float bf2f(unsigned short h) { return __uint_as_float(((unsigned)h) << 16); }
DEVINL unsigned packbf(float a, float b) { return (unsigned)f2bf(a) | ((unsigned)f2bf(b) << 16); }
DEVINL unsigned pk2u(float2 z) { return packbf(z.x, z.y); }
DEVINL ushort2 pk2(float2 z) { return make_ushort2(f2bf(z.x), f2bf(z.y)); }
DEVINL float2 up2(ushort2 u) { return f2(bf2f(u.x), bf2f(u.y)); }
DEVINL float2 upu(unsigned u) { return f2(bf2f((unsigned short)(u & 0xffffu)), bf2f((unsigned short)(u >> 16))); }

typedef __attribute__((ext_vector_type(8))) short short8;
typedef __attribute__((ext_vector_type(4))) float f32x4;
typedef __attribute__((ext_vector_type(4))) float fv4;

// f32 LDS map (float2 elems): row r, elem e; rotation de-aliases the 2KB row stride.
DEVINL int IDX(int r, int e) { return r * 256 + ((e + r) & 255); }
// k34 LDS map: element e (=h) of column r; +r rotation de-aliases the 512B h-stride.
#define OFSID(e, r) ((e) * 128 + (((r) + (e)) & 127))

// ---- in-register 16-point FFT ----
template<int SGN>
DEVINL void fft16r(float2 v[16]) {
  float2 t;
#define SW(a,b) { t = v[a]; v[a] = v[b]; v[b] = t; }
  SW(1, 8) SW(2, 4) SW(3, 12) SW(5, 10) SW(7, 14) SW(11, 13)
#undef SW
  const float C1 = 0.92387953251128674f, C2 = 0.70710678118654752f, C3 = 0.38268343236508977f;
  const float Ct[8] = {1.f, C1, C2, C3, 0.f, -C3, -C2, -C1};
  const float St[8] = {0.f, C3, C2, C1, 1.f, C1, C2, C3};
#pragma unroll
  for (int len = 2; len <= 16; len <<= 1) {
    const int half = len >> 1, ts = 16 / len;
#pragma unroll
    for (int i = 0; i < 16; i += len) {
#pragma unroll
      for (int j = 0; j < half; ++j) {
        const float wr = Ct[j * ts];
        const float wi = (SGN > 0) ? St[j * ts] : -St[j * ts];
        float2 b = v[i + j + half];
        float2 tt = f2(wr * b.x - wi * b.y, wr * b.y + wi * b.x);
        float2 a = v[i + j];
        v[i + j]        = f2(a.x + tt.x, a.y + tt.y);
        v[i + j + half] = f2(a.x - tt.x, a.y - tt.y);
      }
    }
  }
}

template<int SGN>
DEVINL void twiddle16(float2 v[16], int t) {
  const float unit = (SGN > 0) ? 0.024543692606170259f : -0.024543692606170259f;
  float sb, cb;
  __sincosf(unit * (float)t, &sb, &cb);
  float2 W[16];
  W[1] = f2(cb, sb);
#pragma unroll
  for (int k = 2; k < 16; ++k) W[k] = cmul(W[k >> 1], W[k - (k >> 1)]);
#pragma unroll
  for (int k = 1; k < 16; ++k) v[k] = cmul(v[k], W[k]);
}

// ---- f32 256-pt FFT middle, row-local (16-lane slot owns row r) ----
template<int SGN>
DEVINL void fft256_mid(float2 v[16], float2* __restrict__ lds, int r, int t) {
  fft16r<SGN>(v);
  twiddle16<SGN>(v, t);
#pragma unroll
  for (int k = 0; k < 16; ++k) lds[IDX(r, t * 16 + ((k + t) & 15))] = v[k];
#pragma unroll
  for (int n2 = 0; n2 < 16; ++n2) v[n2] = lds[IDX(r, n2 * 16 + ((t + n2) & 15))];
  fft16r<SGN>(v);
}

// ---- K1: per (b, y-pair): 32 row FFTs over x. 512 threads. R: [b][w][y][c] bf16 ----
__global__ __launch_bounds__(512) void k1_rowfft(const float* __restrict__ img, ushort2* __restrict__ R) {
  __shared__ float2 lds[32 * 256];   // 64 KB
  const int tid = threadIdx.x, s = tid >> 4, t = tid & 15;
  const int y0 = blockIdx.x * 2, b = blockIdx.y;
  const float4* ip4 = (const float4*)(img + ((size_t)(b * Hh + y0) * Ww) * Cc);
  for (int i = tid; i < 2 * Ww * 4; i += 512) {
    int yb = i >> 9, rem = i & 511, x = rem >> 2, j = rem & 3;
    float4 u = ip4[(size_t)yb * 512 + rem];
    lds[IDX(yb * 16 + 4 * j + 0, x)] = f2(u.x, 0.f);
    lds[IDX(yb * 16 + 4 * j + 1, x)] = f2(u.y, 0.f);
    lds[IDX(yb * 16 + 4 * j + 2, x)] = f2(u.z, 0.f);
    lds[IDX(yb * 16 + 4 * j + 3, x)] = f2(u.w, 0.f);
  }
  __syncthreads();
  float2 v[16];
#pragma unroll
  for (int j = 0; j < 8; ++j) v[j] = lds[IDX(s, t + 16 * j)];
#pragma unroll
  for (int j = 8; j < 16; ++j) v[j] = f2(0.f, 0.f);
  fft256_mid<-1>(v, lds, s, t);
#pragma unroll
  for (int k = 0; k < 8; ++k) lds[IDX(s, t + 16 * k)] = v[k];
  if (t == 0) lds[IDX(s, 128)] = v[8];
  __syncthreads();
  ushort2* rp = R + ((size_t)b * WH * Hh + y0) * Cc;
  for (int i = tid; i < WH * 32; i += 512) {
    int w = i >> 5, row = i & 31;
    rp[(size_t)w * Hh * Cc + row] = pk2(lds[IDX(row, w)]);
  }
}

// ---- K2: per (w, b-pair): 32 column FFTs over y. 512 threads. Fimg: [h][w][b][c] bf16 ----
__global__ __launch_bounds__(512) void k2_colfft(const ushort2* __restrict__ R, ushort2* __restrict__ Fimg) {
  __shared__ float2 lds[32 * 256];   // 64 KB
  const int tid = threadIdx.x, s = tid >> 4, t = tid & 15;
  const int w = blockIdx.x, b0 = blockIdx.y * 2;
  const uint4* rp4 = (const uint4*)(R + ((size_t)(b0 * WH + w) * Hh) * Cc);
  const size_t bstride4 = (size_t)WH * Hh * Cc / 4;
  for (int i = tid; i < 2 * Hh * 4; i += 512) {
    int bb = i >> 9, rem = i & 511, y = rem >> 2, j = rem & 3;
    uint4 u = rp4[(size_t)bb * bstride4 + rem];
    lds[IDX(bb * 16 + 4 * j + 0, y)] = upu(u.x);
    lds[IDX(bb * 16 + 4 * j + 1, y)] = upu(u.y);
    lds[IDX(bb * 16 + 4 * j + 2, y)] = upu(u.z);
    lds[IDX(bb * 16 + 4 * j + 3, y)] = upu(u.w);
  }
  __syncthreads();
  float2 v[16];
#pragma unroll
  for (int j = 0; j < 8; ++j) v[j] = lds[IDX(s, t + 16 * j)];
#pragma unroll
  for (int j = 8; j < 16; ++j) v[j] = f2(0.f, 0.f);
  fft256_mid<-1>(v, lds, s, t);
#pragma unroll
  for (int k2 = 0; k2 < 16; ++k2) lds[IDX(s, t + 16 * k2)] = v[k2];
  __syncthreads();
  ushort2* fp = Fimg + (size_t)w * 256 + b0 * 16;
  for (int i = tid; i < Nn * 32; i += 512) {
    int h = i >> 5, row = i & 31;
    fp[(size_t)h * WH * 256 + row] = pk2(lds[IDX(row, h)]);
  }
}

// ---- K34: per (bg, w): einsum (MFMA, 4 valid b) for all 256 h -> LDS, then 128 in-place
// column iFFTs over h, crop y' = h-63, coalesced T store. T: [b][y'][w][f] bf16 pairs.
__global__ __launch_bounds__(512) void k34_mulifft(const ushort2* __restrict__ Fimg,
                                                   const float* __restrict__ Kr,
                                                   const float* __restrict__ Ki,
                                                   ushort2* __restrict__ T) {
  __shared__ unsigned ofs[256 * 128];   // 128 KB: [h][r], r = b_loc*32 + f, packed bf16 (re,im)
  const int tid = threadIdx.x;
  const int bg = blockIdx.x, w = blockIdx.y;
  const int b0 = bg * 4;
  const int wv = tid >> 6, ln = tid & 63;
  const int q = ln >> 4, fq = ln & 15, m0 = q & 1;
  const bool hi = (q >= 2);
  const int sh = hi ? 16 : 0;
  const unsigned negmask = hi ? 0x80008000u : 0u;
  union U { unsigned u[4]; short8 s; };

  // ---- phase 1: einsum; wave wv handles h = wv + 8*i ----
  for (int i = 0; i < 32; ++i) {
    const int h = wv + 8 * i;
    const size_t base = (size_t)h * WH + w;
    uint4 a0 = make_uint4(0, 0, 0, 0), a1 = make_uint4(0, 0, 0, 0);
    if (fq < 4) {                                   // A rows 4..15 zero -> D rows 4..15 zero
      const uint4* ap = (const uint4*)(Fimg + base * 256);
      a0 = ap[(b0 + fq) * 4 + 2 * m0];
      a1 = ap[(b0 + fq) * 4 + 2 * m0 + 1];
    }
    const float* kb = Kr + base * 512 + fq * 16 + 8 * m0;
    const float* ib = Ki + base * 512 + fq * 16 + 8 * m0;
    const float4 kr00 = *(const float4*)kb;          const float4 kr01 = *(const float4*)(kb + 4);
    const float4 kr10 = *(const float4*)(kb + 256);  const float4 kr11 = *(const float4*)(kb + 260);
    const float4 ki00 = *(const float4*)ib;          const float4 ki01 = *(const float4*)(ib + 4);
    const float4 ki10 = *(const float4*)(ib + 256);  const float4 ki11 = *(const float4*)(ib + 260);

    U ua;
    ua.u[0] = ((a0.x >> sh) & 0xffffu) | (((a0.y >> sh) & 0xffffu) << 16);
    ua.u[1] = ((a0.z >> sh) & 0xffffu) | (((a0.w >> sh) & 0xffffu) << 16);
    ua.u[2] = ((a1.x >> sh) & 0xffffu) | (((a1.y >> sh) & 0xffffu) << 16);
    ua.u[3] = ((a1.z >> sh) & 0xffffu) | (((a1.w >> sh) & 0xffffu) << 16);

    U ubr0, ubi0, ubr1, ubi1;
    {
      unsigned krP[4] = { packbf(kr00.x, kr00.y), packbf(kr00.z, kr00.w),
                          packbf(kr01.x, kr01.y), packbf(kr01.z, kr01.w) };
      unsigned kiP[4] = { packbf(ki00.x, ki00.y), packbf(ki00.z, ki00.w),
                          packbf(ki01.x, ki01.y), packbf(ki01.z, ki01.w) };
#pragma unroll
      for (int j = 0; j < 4; ++j) {
        ubr0.u[j] = (hi ? kiP[j] : krP[j]) ^ negmask;   // [Kr | -Ki]
        ubi0.u[j] = hi ? krP[j] : kiP[j];               // [Ki |  Kr]
      }
    }
    {
      unsigned krP[4] = { packbf(kr10.x, kr10.y), packbf(kr10.z, kr10.w),
                          packbf(kr11.x, kr11.y), packbf(kr11.z, kr11.w) };
      unsigned kiP[4] = { packbf(ki10.x, ki10.y), packbf(ki10.z, ki10.w),
                          packbf(ki11.x, ki11.y), packbf(ki11.z, ki11.w) };
#pragma unroll
      for (int j = 0; j < 4; ++j) {
        ubr1.u[j] = (hi ? kiP[j] : krP[j]) ^ negmask;
        ubi1.u[j] = hi ? krP[j] : kiP[j];
      }
    }

    f32x4 aR0 = {0.f, 0.f, 0.f, 0.f}, aI0 = {0.f, 0.f, 0.f, 0.f};
    f32x4 aR1 = {0.f, 0.f, 0.f, 0.f}, aI1 = {0.f, 0.f, 0.f, 0.f};
    aR0 = __builtin_amdgcn_mfma_f32_16x16x32_bf16(ua.s, ubr0.s, aR0, 0, 0, 0);
    aI0 = __builtin_amdgcn_mfma_f32_16x16x32_bf16(ua.s, ubi0.s, aI0, 0, 0, 0);
    aR1 = __builtin_amdgcn_mfma_f32_16x16x32_bf16(ua.s, ubr1.s, aR1, 0, 0, 0);
    aI1 = __builtin_amdgcn_mfma_f32_16x16x32_bf16(ua.s, ubi1.s, aI1, 0, 0, 0);

    if (q == 0) {                                   // D rows 0..3 = b_loc 0..3 (lane fq = f)
#pragma unroll
      for (int reg = 0; reg < 4; ++reg) {
        ofs[OFSID(h, reg * 32 + fq)]      = packbf(aR0[reg], aI0[reg]);
        ofs[OFSID(h, reg * 32 + fq + 16)] = packbf(aR1[reg], aI1[reg]);
      }
    }
  }
  __syncthreads();

  // ---- phase 2: 128 in-place column iFFTs; slot s (16 lanes) owns column r ----
  const int s = tid >> 4, t = tid & 15;
#pragma unroll
  for (int round = 0; round < 4; ++round) {
    const int r = s + 32 * round;
    float2 v[16];
#pragma unroll
    for (int j = 0; j < 16; ++j) v[j] = upu(ofs[OFSID(t + 16 * j, r)]);
    fft16r<1>(v);
    twiddle16<1>(v, t);
#pragma unroll
    for (int k = 0; k < 16; ++k) ofs[OFSID(t * 16 + ((k + t) & 15), r)] = pk2u(v[k]);
#pragma unroll
    for (int n2 = 0; n2 < 16; ++n2) v[n2] = upu(ofs[OFSID(n2 * 16 + ((t + n2) & 15), r)]);
    fft16r<1>(v);
#pragma unroll
    for (int k2 = 3; k2 < 12; ++k2) ofs[OFSID(t + 16 * k2, r)] = pk2u(v[k2]);  // 48..191 ⊇ 63..190
  }
  __syncthreads();

  // ---- coalesced T store: per (yp, bb): 32 f x 4B = 128B line ----
  uint4* tpu4 = (uint4*)T;
  for (int i = tid; i < 128 * 32; i += 512) {
    int yp = i >> 5, rr = i & 31;     // rr = bb*8 + j
    int bb = rr >> 3, j = rr & 7;
    uint4 st;
    st.x = ofs[OFSID(63 + yp, bb * 32 + 4 * j + 0)];
    st.y = ofs[OFSID(63 + yp, bb * 32 + 4 * j + 1)];
    st.z = ofs[OFSID(63 + yp, bb * 32 + 4 * j + 2)];
    st.w = ofs[OFSID(63 + yp, bb * 32 + 4 * j + 3)];
    tpu4[((size_t)(b0 + bb) * Hh * WH + (size_t)yp * WH + w) * 8 + j] = st;
  }
}

// ---- K5: per (b,y'): Hermitian-extend w-spectrum, 32 inverse FFTs, Re, scale, +bias, crop x ----
__global__ __launch_bounds__(512) void k5_rowifft(const ushort2* __restrict__ T, const float* __restrict__ bias,
                                                  float* __restrict__ out) {
  __shared__ float2 lds[32 * 256];   // 64 KB
  const int tid = threadIdx.x, s = tid >> 4, t = tid & 15;
  const int yp = blockIdx.x, b = blockIdx.y;
  const uint4* tp4 = (const uint4*)T + ((size_t)(b * Hh + yp) * WH) * 8;
  for (int i = tid; i < WH * 8; i += 512) {
    int w = i >> 3, j = i & 7;
    uint4 u = tp4[(size_t)w * 8 + j];
    lds[IDX(4 * j + 0, w)] = upu(u.x);
    lds[IDX(4 * j + 1, w)] = upu(u.y);
    lds[IDX(4 * j + 2, w)] = upu(u.z);
    lds[IDX(4 * j + 3, w)] = upu(u.w);
  }
  __syncthreads();
  float2 v[16];
#pragma unroll
  for (int n1 = 0; n1 < 16; ++n1) {
    const int c = t + 16 * n1;
    if (c <= 128) v[n1] = lds[IDX(s, c)];
    else { float2 z = lds[IDX(s, 256 - c)]; v[n1] = f2(z.x, -z.y); }
  }
  fft256_mid<1>(v, lds, s, t);
#pragma unroll
  for (int k2 = 3; k2 < 12; ++k2) lds[IDX(s, t + 16 * k2)] = v[k2];
  __syncthreads();
  const float sc = 1.f / 65536.f;
  const int j8 = tid & 7;
  const float bv0 = bias[4 * j8 + 0], bv1 = bias[4 * j8 + 1];
  const float bv2 = bias[4 * j8 + 2], bv3 = bias[4 * j8 + 3];
  fv4* op = (fv4*)(out + ((size_t)(b * Hh + yp) * Ww) * Ff);
  for (int i = tid; i < Ww * 8; i += 512) {
    int x = i >> 3, j = i & 7;
    fv4 st;
    st.x = lds[IDX(4 * j + 0, 63 + x)].x * sc + bv0;
    st.y = lds[IDX(4 * j + 1, 63 + x)].x * sc + bv1;
    st.z = lds[IDX(4 * j + 2, 63 + x)].x * sc + bv2;
    st.w = lds[IDX(4 * j + 3, 63 + x)].x * sc + bv3;
    __builtin_nontemporal_store(st, &op[(size_t)x * 8 + j]);
  }
}

extern "C" void kernel_launch(void* const* d_in, const int* in_sizes, int n_in,
                              void* d_out, int out_size, void* d_ws, size_t ws_size,
                              hipStream_t stream) {
  const float* img  = (const float*)d_in[0];
  const float* kr   = (const float*)d_in[1];
  const float* ki   = (const float*)d_in[2];
  const float* bias = (const float*)d_in[3];
  float* out = (float*)d_out;

  char* ws = (char*)d_ws;
  // region layout:
  //   [0, 33.8MB):       Fimg bf16 (K2 -> K34; must NOT alias T)
  //   [67.6MB, 101.4MB): R bf16 (K1->K2, dead after K2); T bf16 (K34->K5) overwrites it
  const size_t szF = (size_t)Nn * WH * Bn * Cc * sizeof(float2);   // 67,633,152
  ushort2* Fimg = (ushort2*)ws;
  ushort2* R    = (ushort2*)(ws + szF);
  ushort2* T    = (ushort2*)(ws + szF);

  k1_rowfft  <<<dim3(Hh / 2, Bn),  512, 0, stream>>>(img, R);
  k2_colfft  <<<dim3(WH, Bn / 2),  512, 0, stream>>>(R, Fimg);
  k34_mulifft<<<dim3(4, WH),       512, 0, stream>>>(Fimg, kr, ki, T);
  k5_rowifft <<<dim3(Hh, Bn),      512, 0, stream>>>(T, bias, out);
}

// Round 18
// 132.505 us; speedup vs baseline: 1.8103x; 1.8103x over previous
//
#include <hip/hip_runtime.h>
#include <math.h>

// FourierConv2D: B=16,H=W=128,C=16,F=32. FFT 256x256, half-spectrum w in [0,129).
// v17 = v15 revert (best: 133.9us). k1/k2 512-thr full-line stores; k3 = v13 2-wave MFMA;
// k4/k5 512-thr f32-LDS 16B/lane. v16's k3+k4 fusion REGRESSED (4x K re-read) - abandoned.

constexpr int Bn = 16, Cc = 16, Ff = 32, Hh = 128, Ww = 128, Nn = 256, WH = 129;

#define DEVINL __device__ __forceinline__
DEVINL float2 f2(float a, float b) { return make_float2(a, b); }
DEVINL float2 cmul(float2 a, float2 b) { return f2(a.x * b.x - a.y * b.y, a.x * b.y + a.y * b.x); }

DEVINL unsigned short f2bf(float f) { unsigned u = __float_as_uint(f); return (unsigned short)((u + 0x8000u) >> 16); }
DEVINL float bf2f(unsigned short h) { return __uint_as_float(((unsigned)h) << 16); }
DEVINL unsigned packbf(float a, float b) { return (unsigned)f2bf(a) | ((unsigned)f2bf(b) << 16); }
DEVINL unsigned pk2u(float2 z) { return packbf(z.x, z.y); }
DEVINL ushort2 pk2(float2 z) { return make_ushort2(f2bf(z.x), f2bf(z.y)); }
DEVINL float2 up2(ushort2 u) { return f2(bf2f(u.x), bf2f(u.y)); }
DEVINL float2 upu(unsigned u) { return f2(bf2f((unsigned short)(u & 0xffffu)), bf2f((unsigned short)(u >> 16))); }

typedef __attribute__((ext_vector_type(8))) short short8;
typedef __attribute__((ext_vector_type(4))) float f32x4;
typedef __attribute__((ext_vector_type(4))) float fv4;

// f32 LDS map (float2 elems): row r, elem e; rotation de-aliases the 2KB row stride.
DEVINL int IDX(int r, int e) { return r * 256 + ((e + r) & 255); }

// ---- in-register 16-point FFT ----
template<int SGN>
DEVINL void fft16r(float2 v[16]) {
  float2 t;
#define SW(a,b) { t = v[a]; v[a] = v[b]; v[b] = t; }
  SW(1, 8) SW(2, 4) SW(3, 12) SW(5, 10) SW(7, 14) SW(11, 13)
#undef SW
  const float C1 = 0.92387953251128674f, C2 = 0.70710678118654752f, C3 = 0.38268343236508977f;
  const float Ct[8] = {1.f, C1, C2, C3, 0.f, -C3, -C2, -C1};
  const float St[8] = {0.f, C3, C2, C1, 1.f, C1, C2, C3};
#pragma unroll
  for (int len = 2; len <= 16; len <<= 1) {
    const int half = len >> 1, ts = 16 / len;
#pragma unroll
    for (int i = 0; i < 16; i += len) {
#pragma unroll
      for (int j = 0; j < half; ++j) {
        const float wr = Ct[j * ts];
        const float wi = (SGN > 0) ? St[j * ts] : -St[j * ts];
        float2 b = v[i + j + half];
        float2 tt = f2(wr * b.x - wi * b.y, wr * b.y + wi * b.x);
        float2 a = v[i + j];
        v[i + j]        = f2(a.x + tt.x, a.y + tt.y);
        v[i + j + half] = f2(a.x - tt.x, a.y - tt.y);
      }
    }
  }
}

template<int SGN>
DEVINL void twiddle16(float2 v[16], int t) {
  const float unit = (SGN > 0) ? 0.024543692606170259f : -0.024543692606170259f;
  float sb, cb;
  __sincosf(unit * (float)t, &sb, &cb);
  float2 W[16];
  W[1] = f2(cb, sb);
#pragma unroll
  for (int k = 2; k < 16; ++k) W[k] = cmul(W[k >> 1], W[k - (k >> 1)]);
#pragma unroll
  for (int k = 1; k < 16; ++k) v[k] = cmul(v[k], W[k]);
}

// ---- f32 256-pt FFT middle, row-local (16-lane slot owns row r) ----
template<int SGN>
DEVINL void fft256_mid(float2 v[16], float2* __restrict__ lds, int r, int t) {
  fft16r<SGN>(v);
  twiddle16<SGN>(v, t);
#pragma unroll
  for (int k = 0; k < 16; ++k) lds[IDX(r, t * 16 + ((k + t) & 15))] = v[k];
#pragma unroll
  for (int n2 = 0; n2 < 16; ++n2) v[n2] = lds[IDX(r, n2 * 16 + ((t + n2) & 15))];
  fft16r<SGN>(v);
}

// ---- K1: per (b, y-pair): 32 row FFTs over x (rows = yb*16+c). 512 threads.
// R layout: [b][w][y][c] (bf16 pairs); per w a block writes 2y*16c = 128B full line.
__global__ __launch_bounds__(512) void k1_rowfft(const float* __restrict__ img, ushort2* __restrict__ R) {
  __shared__ float2 lds[32 * 256];   // 64 KB
  const int tid = threadIdx.x, s = tid >> 4, t = tid & 15;
  const int y0 = blockIdx.x * 2, b = blockIdx.y;
  const float4* ip4 = (const float4*)(img + ((size_t)(b * Hh + y0) * Ww) * Cc);
  for (int i = tid; i < 2 * Ww * 4; i += 512) {      // 1024 float4
    int yb = i >> 9, rem = i & 511, x = rem >> 2, j = rem & 3;
    float4 u = ip4[(size_t)yb * 512 + rem];
    lds[IDX(yb * 16 + 4 * j + 0, x)] = f2(u.x, 0.f);
    lds[IDX(yb * 16 + 4 * j + 1, x)] = f2(u.y, 0.f);
    lds[IDX(yb * 16 + 4 * j + 2, x)] = f2(u.z, 0.f);
    lds[IDX(yb * 16 + 4 * j + 3, x)] = f2(u.w, 0.f);
  }
  __syncthreads();
  float2 v[16];
#pragma unroll
  for (int j = 0; j < 8; ++j) v[j] = lds[IDX(s, t + 16 * j)];
#pragma unroll
  for (int j = 8; j < 16; ++j) v[j] = f2(0.f, 0.f);
  fft256_mid<-1>(v, lds, s, t);
#pragma unroll
  for (int k = 0; k < 8; ++k) lds[IDX(s, t + 16 * k)] = v[k];
  if (t == 0) lds[IDX(s, 128)] = v[8];
  __syncthreads();
  ushort2* rp = R + ((size_t)b * WH * Hh + y0) * Cc;
  for (int i = tid; i < WH * 32; i += 512) {
    int w = i >> 5, row = i & 31;                    // row = yb*16+c
    rp[(size_t)w * Hh * Cc + row] = pk2(lds[IDX(row, w)]);
  }
}

// ---- K2: per (w, b-pair): 32 column FFTs over y (rows = bb*16+c). 512 threads.
// Fimg layout: [h][w][b][c]; per h a block writes 2b*16c = 128B full line.
__global__ __launch_bounds__(512) void k2_colfft(const ushort2* __restrict__ R, ushort2* __restrict__ Fimg) {
  __shared__ float2 lds[32 * 256];   // 64 KB
  const int tid = threadIdx.x, s = tid >> 4, t = tid & 15;
  const int w = blockIdx.x, b0 = blockIdx.y * 2;
  const uint4* rp4 = (const uint4*)(R + ((size_t)(b0 * WH + w) * Hh) * Cc);
  const size_t bstride4 = (size_t)WH * Hh * Cc / 4;  // uint4 units per b
  for (int i = tid; i < 2 * Hh * 4; i += 512) {      // 1024 uint4
    int bb = i >> 9, rem = i & 511, y = rem >> 2, j = rem & 3;
    uint4 u = rp4[(size_t)bb * bstride4 + rem];
    lds[IDX(bb * 16 + 4 * j + 0, y)] = upu(u.x);
    lds[IDX(bb * 16 + 4 * j + 1, y)] = upu(u.y);
    lds[IDX(bb * 16 + 4 * j + 2, y)] = upu(u.z);
    lds[IDX(bb * 16 + 4 * j + 3, y)] = upu(u.w);
  }
  __syncthreads();
  float2 v[16];
#pragma unroll
  for (int j = 0; j < 8; ++j) v[j] = lds[IDX(s, t + 16 * j)];
#pragma unroll
  for (int j = 8; j < 16; ++j) v[j] = f2(0.f, 0.f);
  fft256_mid<-1>(v, lds, s, t);
#pragma unroll
  for (int k2 = 0; k2 < 16; ++k2) lds[IDX(s, t + 16 * k2)] = v[k2];
  __syncthreads();
  ushort2* fp = Fimg + (size_t)w * 256 + b0 * 16;
  for (int i = tid; i < Nn * 32; i += 512) {
    int h = i >> 5, row = i & 31;                    // row = bb*16+c
    fp[(size_t)h * WH * 256 + row] = pk2(lds[IDX(row, h)]);
  }
}

// ---- K3: per (h,w): out[b,f] = sum_c A[b,c]*(Kr[f,c]+i*Ki[f,c]) via bf16 MFMA (v13) ----
// 2-wave blocks; each wave loads TWO points fully up front, sched_barrier, computes both.
// OF layout: [w][h][b][f~] interleaved (full 128B-line stores).
constexpr int K3PTS = 2;
__global__ __launch_bounds__(128) void k3_mul(const ushort2* __restrict__ Fimg, const float* __restrict__ Kr,
                                              const float* __restrict__ Ki, ushort2* __restrict__ OF) {
  const int tid = threadIdx.x;
  const int wv = tid >> 6, ln = tid & 63;
  const int w = blockIdx.x, h0 = blockIdx.y * (2 * K3PTS) + wv * K3PTS;
  const int q = ln >> 4, fq = ln & 15, m0 = q & 1;
  const bool hi = (q >= 2);
  const int sh = hi ? 16 : 0;
  const unsigned negmask = hi ? 0x80008000u : 0u;

  union U { unsigned u[4]; short8 s; };

  uint4  a0[2], a1[2];
  float4 kA[2], kB[2], kC[2], kD[2];
  float4 iA[2], iB[2], iC[2], iD[2];

  auto load = [&](int g, int p) {
    const size_t base = (size_t)(h0 + g) * WH + w;
    const uint4* ap = (const uint4*)(Fimg + base * 256);
    a0[p] = ap[fq * 4 + 2 * m0];
    a1[p] = ap[fq * 4 + 2 * m0 + 1];
    const float* kb = Kr + base * 512 + fq * 16 + 8 * m0;
    const float* ib = Ki + base * 512 + fq * 16 + 8 * m0;
    kA[p] = *(const float4*)kb;          kB[p] = *(const float4*)(kb + 4);
    kC[p] = *(const float4*)(kb + 256);  kD[p] = *(const float4*)(kb + 260);
    iA[p] = *(const float4*)ib;          iB[p] = *(const float4*)(ib + 4);
    iC[p] = *(const float4*)(ib + 256);  iD[p] = *(const float4*)(ib + 260);
  };

  auto compute = [&](int g, int p) {
    U ua;
    ua.u[0] = ((a0[p].x >> sh) & 0xffffu) | (((a0[p].y >> sh) & 0xffffu) << 16);
    ua.u[1] = ((a0[p].z >> sh) & 0xffffu) | (((a0[p].w >> sh) & 0xffffu) << 16);
    ua.u[2] = ((a1[p].x >> sh) & 0xffffu) | (((a1[p].y >> sh) & 0xffffu) << 16);
    ua.u[3] = ((a1[p].z >> sh) & 0xffffu) | (((a1[p].w >> sh) & 0xffffu) << 16);

    U ubr0, ubi0, ubr1, ubi1;
    {
      unsigned krP[4] = { packbf(kA[p].x, kA[p].y), packbf(kA[p].z, kA[p].w),
                          packbf(kB[p].x, kB[p].y), packbf(kB[p].z, kB[p].w) };
      unsigned kiP[4] = { packbf(iA[p].x, iA[p].y), packbf(iA[p].z, iA[p].w),
                          packbf(iB[p].x, iB[p].y), packbf(iB[p].z, iB[p].w) };
#pragma unroll
      for (int j = 0; j < 4; ++j) {
        ubr0.u[j] = (hi ? kiP[j] : krP[j]) ^ negmask;   // [Kr | -Ki]
        ubi0.u[j] = hi ? krP[j] : kiP[j];               // [Ki |  Kr]
      }
    }
    {
      unsigned krP[4] = { packbf(kC[p].x, kC[p].y), packbf(kC[p].z, kC[p].w),
                          packbf(kD[p].x, kD[p].y), packbf(kD[p].z, kD[p].w) };
      unsigned kiP[4] = { packbf(iC[p].x, iC[p].y), packbf(iC[p].z, iC[p].w),
                          packbf(iD[p].x, iD[p].y), packbf(iD[p].z, iD[p].w) };
#pragma unroll
      for (int j = 0; j < 4; ++j) {
        ubr1.u[j] = (hi ? kiP[j] : krP[j]) ^ negmask;
        ubi1.u[j] = hi ? krP[j] : kiP[j];
      }
    }

    f32x4 aR0 = {0.f, 0.f, 0.f, 0.f}, aI0 = {0.f, 0.f, 0.f, 0.f};
    f32x4 aR1 = {0.f, 0.f, 0.f, 0.f}, aI1 = {0.f, 0.f, 0.f, 0.f};
    aR0 = __builtin_amdgcn_mfma_f32_16x16x32_bf16(ua.s, ubr0.s, aR0, 0, 0, 0);
    aI0 = __builtin_amdgcn_mfma_f32_16x16x32_bf16(ua.s, ubi0.s, aI0, 0, 0, 0);
    aR1 = __builtin_amdgcn_mfma_f32_16x16x32_bf16(ua.s, ubr1.s, aR1, 0, 0, 0);
    aI1 = __builtin_amdgcn_mfma_f32_16x16x32_bf16(ua.s, ubi1.s, aI1, 0, 0, 0);

    uint2* op = (uint2*)(OF + ((size_t)w * 256 + (h0 + g)) * 512);
#pragma unroll
    for (int reg = 0; reg < 4; ++reg)
      op[(4 * q + reg) * 16 + fq] = make_uint2(packbf(aR0[reg], aI0[reg]),
                                               packbf(aR1[reg], aI1[reg]));
  };

  load(0, 0);
  load(1, 1);
  __builtin_amdgcn_sched_barrier(0);
  compute(0, 0);
  compute(1, 1);
}

// ---- K4: per (w,b): 32 inverse column FFTs over h; store y' = h-63 in [0,128) ----
// 512 threads, f32 LDS 64KB, 16B/lane global ops. T layout: [b][y'][w][f] canonical.
__global__ __launch_bounds__(512) void k4_colifft(const ushort2* __restrict__ OF, ushort2* __restrict__ T) {
  __shared__ float2 lds[32 * 256];   // 64 KB
  const int tid = threadIdx.x, s = tid >> 4, t = tid & 15;
  const int bidx = blockIdx.x;
  const int b = bidx & 15, w = bidx >> 4;
  const uint4* ofp4 = (const uint4*)OF + (size_t)w * 32768;   // + h*128 + b*8 + j (uint4 units)
  for (int i = tid; i < Nn * 8; i += 512) {
    int h = i >> 3, j = i & 7;
    uint4 u = ofp4[(size_t)h * 128 + b * 8 + j];
    lds[IDX(2 * j, h)]      = upu(u.x);   // f = 2j
    lds[IDX(2 * j + 16, h)] = upu(u.y);   // f = 2j+16
    lds[IDX(2 * j + 1, h)]  = upu(u.z);   // f = 2j+1
    lds[IDX(2 * j + 17, h)] = upu(u.w);   // f = 2j+17
  }
  __syncthreads();
  float2 v[16];
#pragma unroll
  for (int j = 0; j < 16; ++j) v[j] = lds[IDX(s, t + 16 * j)];
  fft256_mid<1>(v, lds, s, t);
#pragma unroll
  for (int k2 = 3; k2 < 12; ++k2) lds[IDX(s, t + 16 * k2)] = v[k2];  // elems 48..191 cover 63..190
  __syncthreads();
  uint4* tp4 = (uint4*)T + ((size_t)b * Hh * WH + w) * 8;
  for (int i = tid; i < Hh * 8; i += 512) {
    int yp = i >> 3, j = i & 7;
    uint4 st;
    st.x = pk2u(lds[IDX(4 * j + 0, 63 + yp)]);
    st.y = pk2u(lds[IDX(4 * j + 1, 63 + yp)]);
    st.z = pk2u(lds[IDX(4 * j + 2, 63 + yp)]);
    st.w = pk2u(lds[IDX(4 * j + 3, 63 + yp)]);
    tp4[(size_t)yp * WH * 8 + j] = st;
  }
}

// ---- K5: per (b,y'): Hermitian-extend w-spectrum, 32 inverse FFTs, Re, scale, +bias, crop x ----
// 512 threads, f32 LDS 64KB, 16B/lane global ops. out f32 (nontemporal fv4 stores).
__global__ __launch_bounds__(512) void k5_rowifft(const ushort2* __restrict__ T, const float* __restrict__ bias,
                                                  float* __restrict__ out) {
  __shared__ float2 lds[32 * 256];   // 64 KB
  const int tid = threadIdx.x, s = tid >> 4, t = tid & 15;
  const int yp = blockIdx.x, b = blockIdx.y;
  const uint4* tp4 = (const uint4*)T + ((size_t)(b * Hh + yp) * WH) * 8;  // + w*8 + j
  for (int i = tid; i < WH * 8; i += 512) {
    int w = i >> 3, j = i & 7;
    uint4 u = tp4[(size_t)w * 8 + j];
    lds[IDX(4 * j + 0, w)] = upu(u.x);
    lds[IDX(4 * j + 1, w)] = upu(u.y);
    lds[IDX(4 * j + 2, w)] = upu(u.z);
    lds[IDX(4 * j + 3, w)] = upu(u.w);
  }
  __syncthreads();
  float2 v[16];
#pragma unroll
  for (int n1 = 0; n1 < 16; ++n1) {                 // Hermitian mirror folded into reg load
    const int c = t + 16 * n1;
    if (c <= 128) v[n1] = lds[IDX(s, c)];
    else { float2 z = lds[IDX(s, 256 - c)]; v[n1] = f2(z.x, -z.y); }
  }
  fft256_mid<1>(v, lds, s, t);
#pragma unroll
  for (int k2 = 3; k2 < 12; ++k2) lds[IDX(s, t + 16 * k2)] = v[k2];
  __syncthreads();
  const float sc = 1.f / 65536.f;
  const int j8 = tid & 7;
  const float bv0 = bias[4 * j8 + 0], bv1 = bias[4 * j8 + 1];
  const float bv2 = bias[4 * j8 + 2], bv3 = bias[4 * j8 + 3];
  fv4* op = (fv4*)(out + ((size_t)(b * Hh + yp) * Ww) * Ff);   // + x*8 + j (fv4 units)
  for (int i = tid; i < Ww * 8; i += 512) {
    int x = i >> 3, j = i & 7;
    fv4 st;
    st.x = lds[IDX(4 * j + 0, 63 + x)].x * sc + bv0;
    st.y = lds[IDX(4 * j + 1, 63 + x)].x * sc + bv1;
    st.z = lds[IDX(4 * j + 2, 63 + x)].x * sc + bv2;
    st.w = lds[IDX(4 * j + 3, 63 + x)].x * sc + bv3;
    __builtin_nontemporal_store(st, &op[(size_t)x * 8 + j]);
  }
}

extern "C" void kernel_launch(void* const* d_in, const int* in_sizes, int n_in,
                              void* d_out, int out_size, void* d_ws, size_t ws_size,
                              hipStream_t stream) {
  const float* img  = (const float*)d_in[0];
  const float* kr   = (const float*)d_in[1];
  const float* ki   = (const float*)d_in[2];
  const float* bias = (const float*)d_in[3];
  float* out = (float*)d_out;

  char* ws = (char*)d_ws;
  // region layout (lifetime-overlapped):
  //   [0, 67.6MB):     Fimg bf16 (K2->K3, 33.8MB), later T bf16 (K4->K5, 33.8MB)
  //   [67.6MB, 135MB): OF bf16 (K3->K4, 67.6MB); R bf16 (K1->K2, 16.9MB) aliases its head
  const size_t szF = (size_t)Nn * WH * Bn * Cc * sizeof(float2);   // 67,633,152
  ushort2* Fimg = (ushort2*)ws;
  ushort2* T    = (ushort2*)ws;
  ushort2* OF   = (ushort2*)(ws + szF);
  ushort2* R    = (ushort2*)(ws + szF);

  k1_rowfft <<<dim3(Hh / 2, Bn),  512, 0, stream>>>(img, R);
  k2_colfft <<<dim3(WH, Bn / 2),  512, 0, stream>>>(R, Fimg);
  k3_mul    <<<dim3(WH, 64),      128, 0, stream>>>(Fimg, kr, ki, OF);
  k4_colifft<<<dim3(WH * Bn),     512, 0, stream>>>(OF, T);
  k5_rowifft<<<dim3(Hh, Bn),      512, 0, stream>>>(T, bias, out);
}